// Round 1
// baseline (175.603 us; speedup 1.0000x reference)
//
#include <hip/hip_runtime.h>
#include <hip/hip_bf16.h>

// Fused Interaction Estimator: per row (98304 rows of D=256):
//   g_align = relu(LN(gfeat@Wg + bg)); p_align = relu(LN(pfeat@Wp + bp))
//   out = p_align*sigmoid(p_align*(g_align.wa_p)+ba_p) + g_align*sigmoid(g_align*(p_align.wa_g)+ba_g)
// Strategy: prep kernel packs Wg/Wp as bf16 MFMA B-fragments in d_ws (L2-resident);
// main kernel: 32 rows/block, A staged bf16 in LDS (XOR swizzle), 16x16x32 bf16 MFMA,
// everything else fused in registers + small deterministic LDS partial arrays.

typedef float f32x4 __attribute__((ext_vector_type(4)));
typedef short short8 __attribute__((ext_vector_type(8)));

#define D_DIM 256
#define ROWS 32

__device__ __forceinline__ unsigned short f2bf(float x) {
  // round-to-nearest-even f32 -> bf16 (inputs finite)
  unsigned int u = __float_as_uint(x);
  unsigned int r = (u + 0x7FFFu + ((u >> 16) & 1u)) >> 16;
  return (unsigned short)r;
}

__device__ __forceinline__ float sigm(float x) {
  return 1.0f / (1.0f + __expf(-x));
}

// ---------------- prep: pack W (f32 [k][m] row-major) into per-fragment bf16 layout ----------------
// chunk index = (c*8 + t)*64 + l ; chunk holds 8 bf16: B[k = t*32 + (l>>4)*8 + j][m = c*16 + (l&15)]
__global__ __launch_bounds__(256) void pack_w_kernel(const float* __restrict__ Wg,
                                                     const float* __restrict__ Wp,
                                                     unsigned short* __restrict__ outp) {
  int b = blockIdx.x;
  const float* W = (b < 32) ? Wg : Wp;
  unsigned short* o = outp + (b < 32 ? 0 : 65536);
  int chunk = (b & 31) * 256 + threadIdx.x;   // 0..8191 per matrix
  int c = chunk >> 9;
  int rest = chunk & 511;
  int t = rest >> 6;
  int l = rest & 63;
  int m = c * 16 + (l & 15);
  int kb = t * 32 + ((l >> 4) << 3);
  short8 v;
#pragma unroll
  for (int j = 0; j < 8; ++j) v[j] = (short)f2bf(W[(kb + j) * 256 + m]);
  *(short8*)(o + (size_t)chunk * 8) = v;
}

// ---------------- main fused kernel ----------------

__device__ __forceinline__ short8 readA(const unsigned short* smA, int rt, int t, int lane) {
  int row = rt * 16 + (lane & 15);
  int off = (row * 512 + t * 64 + ((lane >> 4) << 4)) ^ ((row & 7) << 4);
  return *(const short8*)((const char*)smA + off);
}

__device__ __forceinline__ void stageA(const float* __restrict__ src, unsigned short* smA, int tid) {
  const float4* s4 = (const float4*)src;
#pragma unroll
  for (int it = 0; it < 8; ++it) {
    int idx = it * 256 + tid;      // float4 index, 2048 total
    int row = idx >> 6;
    int k4 = (idx & 63) << 2;
    float4 v = s4[idx];
    ushort4 h;
    h.x = f2bf(v.x); h.y = f2bf(v.y); h.z = f2bf(v.z); h.w = f2bf(v.w);
    int off = (row * 512 + k4 * 2) ^ ((row & 7) << 4);
    *(ushort4*)((char*)smA + off) = h;
  }
}

__device__ __forceinline__ void gemm8(f32x4 acc[2][4], const unsigned short* smA,
                                      const short8* __restrict__ wb, int lane, int w) {
  const int bbase = w * 2048 + lane;
#pragma unroll
  for (int t = 0; t < 8; ++t) {
    short8 a0 = readA(smA, 0, t, lane);
    short8 a1 = readA(smA, 1, t, lane);
#pragma unroll
    for (int ct = 0; ct < 4; ++ct) {
      short8 bfr = wb[bbase + ct * 512 + t * 64];
      acc[0][ct] = __builtin_amdgcn_mfma_f32_16x16x32_bf16(a0, bfr, acc[0][ct], 0, 0, 0);
      acc[1][ct] = __builtin_amdgcn_mfma_f32_16x16x32_bf16(a1, bfr, acc[1][ct], 0, 0, 0);
    }
  }
}

// bias add + per-row sum/sumsq partials (deterministic: per-wave slots, no atomics)
__device__ __forceinline__ void statsPhase(f32x4 acc[2][4], const float* __restrict__ bias,
                                           float smSum[4][32], float smSq[4][32],
                                           int lane, int w) {
  float bv[4];
#pragma unroll
  for (int ct = 0; ct < 4; ++ct) bv[ct] = bias[w * 64 + ct * 16 + (lane & 15)];
#pragma unroll
  for (int rt = 0; rt < 2; ++rt) {
#pragma unroll
    for (int r = 0; r < 4; ++r) {
      float s = 0.f, qq = 0.f;
#pragma unroll
      for (int ct = 0; ct < 4; ++ct) {
        float y = acc[rt][ct][r] + bv[ct];
        acc[rt][ct][r] = y;
        s += y; qq += y * y;
      }
#pragma unroll
      for (int m = 1; m < 16; m <<= 1) {
        s += __shfl_xor(s, m, 64);
        qq += __shfl_xor(qq, m, 64);
      }
      if ((lane & 15) == 0) {
        int row = rt * 16 + ((lane >> 4) << 2) + r;
        smSum[w][row] = s;
        smSq[w][row] = qq;
      }
    }
  }
}

// LN + ReLU into outAl; also per-row dot(align, wa) partials into smRed
__device__ __forceinline__ void applyPhase(f32x4 acc[2][4], f32x4 outAl[2][4],
                                           const float* __restrict__ gam, const float* __restrict__ bet,
                                           const float* __restrict__ wa,
                                           const float smSum[4][32], const float smSq[4][32],
                                           float smRed[4][32], int lane, int w) {
  int cb = w * 64 + (lane & 15);
  float gv[4], tv[4], wv[4];
#pragma unroll
  for (int ct = 0; ct < 4; ++ct) {
    gv[ct] = gam[cb + ct * 16];
    tv[ct] = bet[cb + ct * 16];
    wv[ct] = wa[cb + ct * 16];
  }
#pragma unroll
  for (int rt = 0; rt < 2; ++rt) {
#pragma unroll
    for (int r = 0; r < 4; ++r) {
      int row = rt * 16 + ((lane >> 4) << 2) + r;
      float s  = smSum[0][row] + smSum[1][row] + smSum[2][row] + smSum[3][row];
      float qq = smSq[0][row] + smSq[1][row] + smSq[2][row] + smSq[3][row];
      float mu = s * (1.0f / 256.0f);
      float var = qq * (1.0f / 256.0f) - mu * mu;
      var = fmaxf(var, 0.0f);
      float rs = rsqrtf(var + 1e-5f);
      float dp = 0.f;
#pragma unroll
      for (int ct = 0; ct < 4; ++ct) {
        float a = (acc[rt][ct][r] - mu) * rs * gv[ct] + tv[ct];
        a = fmaxf(a, 0.0f);
        outAl[rt][ct][r] = a;
        dp += a * wv[ct];
      }
#pragma unroll
      for (int m = 1; m < 16; m <<= 1) dp += __shfl_xor(dp, m, 64);
      if ((lane & 15) == 0) smRed[w][row] = dp;
    }
  }
}

__global__ __launch_bounds__(256) void fused_main(
    const float* __restrict__ gfeat, const float* __restrict__ pfeat,
    const float* __restrict__ bg, const float* __restrict__ glng, const float* __restrict__ glnb,
    const float* __restrict__ bp, const float* __restrict__ plng, const float* __restrict__ plnb,
    const float* __restrict__ wag, const float* __restrict__ bag,
    const float* __restrict__ wap, const float* __restrict__ bap,
    const unsigned short* __restrict__ wpk,   // g packed at 0, p packed at +65536
    float* __restrict__ outp)
{
  __shared__ unsigned short smA[ROWS * D_DIM];  // 16 KB, XOR-swizzled bf16 rows
  __shared__ float smSum[4][32];
  __shared__ float smSq[4][32];
  __shared__ float smRedG[4][32];   // g_align . wa_p  partials
  __shared__ float smRedP[4][32];   // p_align . wa_g  partials

  const int tid = threadIdx.x;
  const int lane = tid & 63;
  const int w = tid >> 6;
  const int row0 = blockIdx.x * ROWS;

  // ---- branch g: stage A, GEMM, stats ----
  stageA(gfeat + (size_t)row0 * D_DIM, smA, tid);
  __syncthreads();

  f32x4 acc[2][4];
#pragma unroll
  for (int rt = 0; rt < 2; ++rt)
#pragma unroll
    for (int ct = 0; ct < 4; ++ct) acc[rt][ct] = {0.f, 0.f, 0.f, 0.f};

  gemm8(acc, smA, (const short8*)wpk, lane, w);
  statsPhase(acc, bg, smSum, smSq, lane, w);
  __syncthreads();   // stats visible; smA reads done

  // overlap: stage p while applying LN to g
  stageA(pfeat + (size_t)row0 * D_DIM, smA, tid);

  f32x4 alignG[2][4];
  applyPhase(acc, alignG, glng, glnb, wap, smSum, smSq, smRedG, lane, w);
  __syncthreads();   // smA(p) staged; smRedG visible (read only after 2 more barriers)

  // ---- branch p ----
#pragma unroll
  for (int rt = 0; rt < 2; ++rt)
#pragma unroll
    for (int ct = 0; ct < 4; ++ct) acc[rt][ct] = {0.f, 0.f, 0.f, 0.f};

  gemm8(acc, smA, (const short8*)(wpk + 65536), lane, w);
  statsPhase(acc, bp, smSum, smSq, lane, w);
  __syncthreads();

  applyPhase(acc, acc, plng, plnb, wag, smSum, smSq, smRedP, lane, w);  // in-place: acc becomes p_align
  __syncthreads();

  // ---- fusion + store ----
  const float vbag = bag[0], vbap = bap[0];
#pragma unroll
  for (int rt = 0; rt < 2; ++rt) {
#pragma unroll
    for (int r = 0; r < 4; ++r) {
      int row = rt * 16 + ((lane >> 4) << 2) + r;
      float gr = smRedG[0][row] + smRedG[1][row] + smRedG[2][row] + smRedG[3][row];
      float pr = smRedP[0][row] + smRedP[1][row] + smRedP[2][row] + smRedP[3][row];
      float* orow = outp + (size_t)(row0 + row) * D_DIM + w * 64 + (lane & 15);
#pragma unroll
      for (int ct = 0; ct < 4; ++ct) {
        float ga = alignG[rt][ct][r];
        float pa = acc[rt][ct][r];
        float geno = sigm(ga * pr + vbag);
        float path = sigm(pa * gr + vbap);
        orow[ct * 16] = pa * path + ga * geno;
      }
    }
  }
}

extern "C" void kernel_launch(void* const* d_in, const int* in_sizes, int n_in,
                              void* d_out, int out_size, void* d_ws, size_t ws_size,
                              hipStream_t stream) {
  const float* gfeat = (const float*)d_in[0];
  const float* pfeat = (const float*)d_in[1];
  const float* Wg   = (const float*)d_in[2];
  const float* bg   = (const float*)d_in[3];
  const float* glng = (const float*)d_in[4];
  const float* glnb = (const float*)d_in[5];
  const float* Wp   = (const float*)d_in[6];
  const float* bp   = (const float*)d_in[7];
  const float* plng = (const float*)d_in[8];
  const float* plnb = (const float*)d_in[9];
  const float* wag  = (const float*)d_in[10];
  const float* bag  = (const float*)d_in[11];
  const float* wap  = (const float*)d_in[12];
  const float* bap  = (const float*)d_in[13];
  float* outp = (float*)d_out;
  unsigned short* wpk = (unsigned short*)d_ws;   // 256 KB used

  hipLaunchKernelGGL(pack_w_kernel, dim3(64), dim3(256), 0, stream, Wg, Wp, wpk);

  int nrows = in_sizes[0] / D_DIM;        // B*L = 98304
  int nblocks = nrows / ROWS;             // 3072
  hipLaunchKernelGGL(fused_main, dim3(nblocks), dim3(256), 0, stream,
                     gfeat, pfeat, bg, glng, glnb, bp, plng, plnb,
                     wag, bag, wap, bap, wpk, outp);
}